// Round 10
// baseline (302.613 us; speedup 1.0000x reference)
//
#include <hip/hip_runtime.h>
#include <math.h>

// ---------------------------------------------------------------------------
// GCN forward: 3x GCNConv (sym-norm, self-loops) + linear + global max pool.
// N=50000, E=800000, F=256, H=128, O=64. fp32 in/out, fp16 intermediates.
//
// R10: algebraic fusion of the tail — z = Â(h2·Wc) + bc, Wc = W2@Wlin,
// bc = b2@Wlin + blin. Layer-3 GEMM projects to 64 dims BEFORE aggregation:
// agg3 gathers 128B rows (1 line/edge, was 2) and fuses the global max pool
// (per-block LDS max -> pmax -> small reduce). gemm_max eliminated.
// GEMMs: fp16 MFMA, A in LDS (24KB, 4 blk/CU), B direct from L2 pre-pack.
// Graph build: LDS multisplit + per-bucket counting sort (atomic-free).
// ---------------------------------------------------------------------------

typedef __attribute__((ext_vector_type(8))) _Float16 f16x8;
typedef __attribute__((ext_vector_type(4))) _Float16 f16x4;
typedef __attribute__((ext_vector_type(4))) float f32x4;

__device__ __forceinline__ unsigned enc_f32(float f) {
    unsigned u = __float_as_uint(f);
    return (u & 0x80000000u) ? ~u : (u | 0x80000000u);
}
__device__ __forceinline__ float dec_f32(unsigned e) {
    return (e & 0x80000000u) ? __uint_as_float(e & 0x7fffffffu)
                             : __uint_as_float(~e);
}
#define ENC_NEG_INF 0x007FFFFFu  // enc(-inf)

// ------------------------------------------------------- graph build, pass A
__global__ __launch_bounds__(256) void k_hist(const int* __restrict__ dst,
                                              int* __restrict__ T,
                                              int E, int NB, int chunk) {
    __shared__ int hist[512];
    for (int i = threadIdx.x; i < 512; i += 256) hist[i] = 0;
    __syncthreads();
    const int lo = blockIdx.x * chunk, hi = min(E, lo + chunk);
    for (int e = lo + threadIdx.x; e < hi; e += 256)
        atomicAdd(&hist[dst[e] >> 7], 1);
    __syncthreads();
    for (int b = threadIdx.x; b < NB; b += 256)
        T[b * 256 + blockIdx.x] = hist[b];
}

// ------------------------------------------------------------- 3-pass scan
__global__ __launch_bounds__(1024) void k_scan1(const int* __restrict__ in,
                                                int* __restrict__ excl,
                                                int* __restrict__ bsums, int L) {
    __shared__ int sh[1024];
    int t = threadIdx.x;
    int i = blockIdx.x * 1024 + t;
    int v = (i < L) ? in[i] : 0;
    sh[t] = v;
    __syncthreads();
    for (int off = 1; off < 1024; off <<= 1) {
        int tv = (t >= off) ? sh[t - off] : 0;
        __syncthreads();
        sh[t] += tv;
        __syncthreads();
    }
    if (i < L) excl[i] = sh[t] - v;
    if (t == 1023) bsums[blockIdx.x] = sh[1023];
}

__global__ __launch_bounds__(1024) void k_scan2(const int* __restrict__ bsums,
                                                int* __restrict__ bofs, int nb) {
    __shared__ int sh[1024];
    int t = threadIdx.x;
    int v = (t < nb) ? bsums[t] : 0;
    sh[t] = v;
    __syncthreads();
    for (int off = 1; off < 1024; off <<= 1) {
        int tv = (t >= off) ? sh[t - off] : 0;
        __syncthreads();
        sh[t] += tv;
        __syncthreads();
    }
    if (t < nb) bofs[t] = sh[t] - v;
}

__global__ void k_scan3(int* __restrict__ arr, const int* __restrict__ bofs, int L) {
    int i = blockIdx.x * blockDim.x + threadIdx.x;
    if (i < L) arr[i] += bofs[i >> 10];
}

// ------------------------------------------------------- graph build, pass B
#define PBT 4096
__global__ __launch_bounds__(256) void k_part(const int* __restrict__ src,
                                              const int* __restrict__ dst,
                                              const int* __restrict__ T2,
                                              unsigned* __restrict__ eb,
                                              int E, int NB, int chunk) {
    __shared__ int hist[512], lexc[512], pos[512], wpos[512];
    __shared__ unsigned sorted[PBT];
    const int t = threadIdx.x;
    const int blk = blockIdx.x;
    const int lo = blk * chunk, hi = min(E, lo + chunk);
    for (int i = t; i < NB; i += 256) wpos[i] = T2[i * 256 + blk];
    __syncthreads();
    for (int tlo = lo; tlo < hi; tlo += PBT) {
        const int thi = min(hi, tlo + PBT);
        const int sz = thi - tlo;
        for (int i = t; i < 512; i += 256) hist[i] = 0;
        __syncthreads();
        for (int e = tlo + t; e < thi; e += 256)
            atomicAdd(&hist[dst[e] >> 7], 1);
        __syncthreads();
        const int i0 = t, i1 = t + 256;
        const int o0 = hist[i0], o1 = hist[i1];
        for (int off = 1; off < 512; off <<= 1) {
            int v0 = (i0 >= off) ? hist[i0 - off] : 0;
            int v1 = (i1 >= off) ? hist[i1 - off] : 0;
            __syncthreads();
            hist[i0] += v0;
            hist[i1] += v1;
            __syncthreads();
        }
        lexc[i0] = hist[i0] - o0; pos[i0] = hist[i0] - o0;
        lexc[i1] = hist[i1] - o1; pos[i1] = hist[i1] - o1;
        __syncthreads();
        for (int e = tlo + t; e < thi; e += 256) {
            int d = dst[e];
            int p = atomicAdd(&pos[d >> 7], 1);
            sorted[p] = ((unsigned)d << 16) | (unsigned)src[e];
        }
        __syncthreads();
        for (int i = t; i < sz; i += 256) {
            unsigned x = sorted[i];
            int b = (int)(x >> 23);
            eb[wpos[b] + (i - lexc[b])] = x;
        }
        __syncthreads();
        wpos[i0] += o0;
        wpos[i1] += o1;
        __syncthreads();
    }
}

// ------------------------------------------------------- graph build, pass C
#define PCT 6144
__global__ __launch_bounds__(256) void k_build(const unsigned* __restrict__ eb,
                                               const int* __restrict__ T2,
                                               unsigned short* __restrict__ csr,
                                               int* __restrict__ rofs,
                                               float* __restrict__ dinv,
                                               int N, int E, int NB) {
    __shared__ int hist[128], lofs[128], pos[128];
    __shared__ unsigned short ssrc[PCT];
    const int t = threadIdx.x;
    const int b = blockIdx.x;
    const int glo = T2[b * 256];
    const int ghi = (b + 1 < NB) ? T2[(b + 1) * 256] : E;
    const int sz = ghi - glo;
    if (t < 128) hist[t] = 0;
    __syncthreads();
    for (int i = t; i < sz; i += 256)
        atomicAdd(&hist[(eb[glo + i] >> 16) & 127], 1);
    __syncthreads();
    const int o = (t < 128) ? hist[t] : 0;
    for (int off = 1; off < 128; off <<= 1) {
        int v = (t < 128 && t >= off) ? hist[t - off] : 0;
        __syncthreads();
        if (t < 128) hist[t] += v;
        __syncthreads();
    }
    if (t < 128) {
        int ex = hist[t] - o;
        lofs[t] = ex;
        pos[t] = ex;
        int d = b * 128 + t;
        if (d < N) {
            rofs[d] = glo + ex;
            dinv[d] = rsqrtf((float)(o + 1));
        }
    }
    __syncthreads();
    if (sz <= PCT) {
        for (int i = t; i < sz; i += 256) {
            unsigned x = eb[glo + i];
            int p = atomicAdd(&pos[(x >> 16) & 127], 1);
            ssrc[p] = (unsigned short)(x & 0xFFFFu);
        }
        __syncthreads();
        for (int i = t; i < sz; i += 256) csr[glo + i] = ssrc[i];
    } else {
        for (int i = t; i < sz; i += 256) {
            unsigned x = eb[glo + i];
            int p = atomicAdd(&pos[(x >> 16) & 127], 1);
            csr[glo + p] = (unsigned short)(x & 0xFFFFu);
        }
    }
    if (b == 0 && t == 0) rofs[N] = E;
}

// --------------------------------------------- fused weight packing + init
__device__ __forceinline__ void packw_tile(const float* W, _Float16* Wp,
                                           int K, int M, int c, int q, int l) {
    int n = c * 16 + (l & 15);
    int k0 = q * 32 + (l >> 4) * 8;
    size_t base = ((size_t)(c * (K / 32) + q) * 64 + l) * 8;
#pragma unroll
    for (int j = 0; j < 8; ++j)
        Wp[base + j] = (_Float16)W[(size_t)(k0 + j) * M + n];
}

__global__ __launch_bounds__(64) void k_pack_all(const float* __restrict__ W0,
                                                 const float* __restrict__ W1,
                                                 const float* __restrict__ W2,
                                                 _Float16* __restrict__ w0p,
                                                 _Float16* __restrict__ w1p,
                                                 _Float16* __restrict__ w2p,
                                                 unsigned* __restrict__ gmax) {
    int b = blockIdx.x, l = threadIdx.x;
    if (b < 64) {
        packw_tile(W0, w0p, 256, 128, b & 7, b >> 3, l);
    } else if (b < 96) {
        int bb = b - 64;
        packw_tile(W1, w1p, 128, 128, bb & 7, bb >> 3, l);
    } else if (b < 128) {
        int bb = b - 96;
        packw_tile(W2, w2p, 128, 128, bb & 7, bb >> 3, l);
    } else {
        gmax[l] = ENC_NEG_INF;
    }
}

// --------------------------------- fused tail weights: Wc = W2@Wlin (packed),
// bc = b2@Wlin + blin. Blocks 0..15: one (c,q) frag tile each; block 16: bc.
__global__ __launch_bounds__(64) void k_wc(const float* __restrict__ W2,
                                           const float* __restrict__ Wlin,
                                           const float* __restrict__ b2,
                                           const float* __restrict__ blin,
                                           _Float16* __restrict__ wcp,
                                           float* __restrict__ bc) {
    const int l = threadIdx.x;
    if (blockIdx.x == 16) {
        float s = blin[l];
        for (int k = 0; k < 128; ++k) s = fmaf(b2[k], Wlin[k * 64 + l], s);
        bc[l] = s;
        return;
    }
    const int c = blockIdx.x & 3;
    const int q = blockIdx.x >> 2;
    const int n = c * 16 + (l & 15);
    const int k0 = q * 32 + (l >> 4) * 8;
    size_t base = ((size_t)(c * 4 + q) * 64 + l) * 8;  // K/32 = 4
#pragma unroll
    for (int j = 0; j < 8; ++j) {
        float s = 0.f;
        const float* w2row = &W2[(size_t)(k0 + j) * 128];
        for (int m = 0; m < 128; ++m) s = fmaf(w2row[m], Wlin[m * 64 + n], s);
        wcp[base + j] = (_Float16)s;
    }
}

// -------------------------------------------------------------------- GEMM
// 96-row block tile, 4 waves in 2x2 (wave: 48 rows x M/2 cols).
// A staged in LDS (XOR-swizzled frag order); B frags direct from global
// pre-pack (L2-resident, coalesced 16B/lane). out fp16[N][M] = sc[r]*(A W).
// ADT=0: A fp32 [N][K].  ADT=1: A fp16 [N][K].
template <int K, int M, int ADT>
__global__ __launch_bounds__(256, 4) void k_gemm(const void* __restrict__ Av,
                                                 const _Float16* __restrict__ Wp,
                                                 const float* __restrict__ sc,
                                                 _Float16* __restrict__ out,
                                                 int N) {
    constexpr int KB = (K > 128) ? 128 : K;
    constexpr int NQ = K / KB;
    constexpr int NK = KB / 32;
    constexpr int KG = KB / 8;
    constexpr int CT = M / 32;
    constexpr int RT = 3;
    __shared__ _Float16 As[96 * KB];
    const int tid = threadIdx.x;
    const int lane = tid & 63;
    const int wave = tid >> 6;
    const int wrow = wave >> 1;
    const int wcol = wave & 1;
    const int R0 = blockIdx.x * 96;

    f32x4 acc[RT][CT];
#pragma unroll
    for (int rt = 0; rt < RT; ++rt)
#pragma unroll
        for (int ct = 0; ct < CT; ++ct) acc[rt][ct] = (f32x4){0.f, 0.f, 0.f, 0.f};

    for (int q = 0; q < NQ; ++q) {
        if (q) __syncthreads();
        if (ADT == 0) {
            const float* A = (const float*)Av;
#pragma unroll
            for (int it = 0; it < (96 * KB) / (4 * 256); ++it) {
                int idx = tid + it * 256;
                int r = idx >> 5;
                int f4 = idx & 31;
                float4 g = {0.f, 0.f, 0.f, 0.f};
                if (R0 + r < N) g = *(const float4*)&A[(size_t)(R0 + r) * K + q * KB + f4 * 4];
                int kg = f4 >> 1, sub = f4 & 1;
                f16x4 h;
                h[0] = (_Float16)g.x; h[1] = (_Float16)g.y;
                h[2] = (_Float16)g.z; h[3] = (_Float16)g.w;
                *(f16x4*)&As[(r >> 4) * (KG * 128) + kg * 128 + (((r & 15) ^ kg) * 8) + sub * 4] = h;
            }
        } else {
            const _Float16* A = (const _Float16*)Av;
#pragma unroll
            for (int it = 0; it < (96 * KB) / (8 * 256); ++it) {
                int idx = tid + it * 256;
                int r = idx / KG;
                int kg = idx % KG;
                uint4 g = {0u, 0u, 0u, 0u};
                if (R0 + r < N) g = *(const uint4*)&A[(size_t)(R0 + r) * K + q * KB + kg * 8];
                *(uint4*)&As[(r >> 4) * (KG * 128) + kg * 128 + (((r & 15) ^ kg) * 8)] = g;
            }
        }
        __syncthreads();
#pragma unroll
        for (int qq = 0; qq < NK; ++qq) {
            const int kk = q * NK + qq;
            const int kgq = qq * 4 + (lane >> 4);
            f16x8 af[RT], bf[CT];
#pragma unroll
            for (int ct = 0; ct < CT; ++ct) {
                int t = wcol * CT + ct;
                bf[ct] = *(const f16x8*)&Wp[((size_t)(t * (K / 32) + kk) * 64 + lane) * 8];
            }
#pragma unroll
            for (int rt = 0; rt < RT; ++rt) {
                int tr = wrow * RT + rt;
                af[rt] = *(const f16x8*)&As[tr * (KG * 128) + kgq * 128 + (((lane & 15) ^ kgq) * 8)];
            }
#pragma unroll
            for (int rt = 0; rt < RT; ++rt)
#pragma unroll
                for (int ct = 0; ct < CT; ++ct)
                    acc[rt][ct] = __builtin_amdgcn_mfma_f32_16x16x32_f16(af[rt], bf[ct], acc[rt][ct], 0, 0, 0);
        }
    }

    const int quad = lane >> 4;
#pragma unroll
    for (int rt = 0; rt < RT; ++rt)
#pragma unroll
        for (int reg = 0; reg < 4; ++reg) {
            int r = R0 + wrow * 48 + rt * 16 + quad * 4 + reg;
            if (r < N) {
                float s = sc[r];
#pragma unroll
                for (int ct = 0; ct < CT; ++ct) {
                    int c = wcol * (CT * 16) + ct * 16 + (lane & 15);
                    out[(size_t)r * M + c] = (_Float16)(acc[rt][ct][reg] * s);
                }
            }
        }
}

// ------------------------------------------------------------- aggregation
// Layers 1-2: fp16 256B rows (2 lines/edge). Wave per dst: 4 edge slots x
// 16 lanes x 16B. fp32 accum, shfl combine, fp16 row write.
__global__ __launch_bounds__(256) void k_agg(const _Float16* __restrict__ tmp,
                                             const float* __restrict__ dinv,
                                             const int* __restrict__ rofs,
                                             const unsigned short* __restrict__ csr,
                                             const float* __restrict__ bias,
                                             _Float16* __restrict__ out, int N) {
    const int lane = threadIdx.x & 63;
    const int d = blockIdx.x * 4 + (threadIdx.x >> 6);
    if (d >= N) return;
    const int eh = lane >> 4;
    const int fl = lane & 15;
    const int beg = rofs[d], end = rofs[d + 1];
    float a[8];
#pragma unroll
    for (int j = 0; j < 8; ++j) a[j] = 0.f;

    int e = beg;
    for (; e + 16 <= end; e += 16) {
        int s0 = csr[e + eh];
        int s1 = csr[e + 4 + eh];
        int s2 = csr[e + 8 + eh];
        int s3 = csr[e + 12 + eh];
        f16x8 v0 = *(const f16x8*)&tmp[(size_t)s0 * 128 + fl * 8];
        f16x8 v1 = *(const f16x8*)&tmp[(size_t)s1 * 128 + fl * 8];
        f16x8 v2 = *(const f16x8*)&tmp[(size_t)s2 * 128 + fl * 8];
        f16x8 v3 = *(const f16x8*)&tmp[(size_t)s3 * 128 + fl * 8];
#pragma unroll
        for (int j = 0; j < 8; ++j) a[j] += (float)v0[j];
#pragma unroll
        for (int j = 0; j < 8; ++j) a[j] += (float)v1[j];
#pragma unroll
        for (int j = 0; j < 8; ++j) a[j] += (float)v2[j];
#pragma unroll
        for (int j = 0; j < 8; ++j) a[j] += (float)v3[j];
    }
    for (; e + 4 <= end; e += 4) {
        int s = csr[e + eh];
        f16x8 v = *(const f16x8*)&tmp[(size_t)s * 128 + fl * 8];
#pragma unroll
        for (int j = 0; j < 8; ++j) a[j] += (float)v[j];
    }
    if (eh < end - e) {
        int s = csr[e + eh];
        f16x8 v = *(const f16x8*)&tmp[(size_t)s * 128 + fl * 8];
#pragma unroll
        for (int j = 0; j < 8; ++j) a[j] += (float)v[j];
    }
    if (eh == 3) {  // self-loop
        f16x8 v = *(const f16x8*)&tmp[(size_t)d * 128 + fl * 8];
#pragma unroll
        for (int j = 0; j < 8; ++j) a[j] += (float)v[j];
    }
#pragma unroll
    for (int j = 0; j < 8; ++j) {
        a[j] += __shfl_xor(a[j], 16, 64);
        a[j] += __shfl_xor(a[j], 32, 64);
    }
    if (eh == 0) {
        float di = dinv[d];
        float4 b0 = *(const float4*)&bias[fl * 8];
        float4 b1 = *(const float4*)&bias[fl * 8 + 4];
        f16x8 o;
        o[0] = (_Float16)fmaf(di, a[0], b0.x);
        o[1] = (_Float16)fmaf(di, a[1], b0.y);
        o[2] = (_Float16)fmaf(di, a[2], b0.z);
        o[3] = (_Float16)fmaf(di, a[3], b0.w);
        o[4] = (_Float16)fmaf(di, a[4], b1.x);
        o[5] = (_Float16)fmaf(di, a[5], b1.y);
        o[6] = (_Float16)fmaf(di, a[6], b1.z);
        o[7] = (_Float16)fmaf(di, a[7], b1.w);
        *(f16x8*)&out[(size_t)d * 128 + fl * 8] = o;
    }
}

// ------------------------------------- layer-3 aggregation + fused max pool
// tmp64: fp16 [N][64] (128B rows = 1 line/edge). Wave per dst: 4 edge slots
// x 16 lanes x 8B (f16x4). Per-block max of z = dinv*S into pmax (encoded).
__global__ __launch_bounds__(256) void k_agg64max(const _Float16* __restrict__ tmp,
                                                  const float* __restrict__ dinv,
                                                  const int* __restrict__ rofs,
                                                  const unsigned short* __restrict__ csr,
                                                  unsigned* __restrict__ pmax,
                                                  int N) {
    __shared__ unsigned smax[64];
    const int tid = threadIdx.x;
    const int lane = tid & 63;
    const int d = blockIdx.x * 4 + (tid >> 6);
    const int eh = lane >> 4;
    const int fl = lane & 15;
    const bool active = (d < N);
    if (tid < 64) smax[tid] = ENC_NEG_INF;
    __syncthreads();

    float a[4] = {0.f, 0.f, 0.f, 0.f};
    if (active) {
        const int beg = rofs[d], end = rofs[d + 1];
        int e = beg;
        for (; e + 16 <= end; e += 16) {
            int s0 = csr[e + eh];
            int s1 = csr[e + 4 + eh];
            int s2 = csr[e + 8 + eh];
            int s3 = csr[e + 12 + eh];
            f16x4 v0 = *(const f16x4*)&tmp[(size_t)s0 * 64 + fl * 4];
            f16x4 v1 = *(const f16x4*)&tmp[(size_t)s1 * 64 + fl * 4];
            f16x4 v2 = *(const f16x4*)&tmp[(size_t)s2 * 64 + fl * 4];
            f16x4 v3 = *(const f16x4*)&tmp[(size_t)s3 * 64 + fl * 4];
#pragma unroll
            for (int j = 0; j < 4; ++j) a[j] += (float)v0[j];
#pragma unroll
            for (int j = 0; j < 4; ++j) a[j] += (float)v1[j];
#pragma unroll
            for (int j = 0; j < 4; ++j) a[j] += (float)v2[j];
#pragma unroll
            for (int j = 0; j < 4; ++j) a[j] += (float)v3[j];
        }
        for (; e + 4 <= end; e += 4) {
            int s = csr[e + eh];
            f16x4 v = *(const f16x4*)&tmp[(size_t)s * 64 + fl * 4];
#pragma unroll
            for (int j = 0; j < 4; ++j) a[j] += (float)v[j];
        }
        if (eh < end - e) {
            int s = csr[e + eh];
            f16x4 v = *(const f16x4*)&tmp[(size_t)s * 64 + fl * 4];
#pragma unroll
            for (int j = 0; j < 4; ++j) a[j] += (float)v[j];
        }
        if (eh == 3) {  // self-loop
            f16x4 v = *(const f16x4*)&tmp[(size_t)d * 64 + fl * 4];
#pragma unroll
            for (int j = 0; j < 4; ++j) a[j] += (float)v[j];
        }
    }
#pragma unroll
    for (int j = 0; j < 4; ++j) {
        a[j] += __shfl_xor(a[j], 16, 64);
        a[j] += __shfl_xor(a[j], 32, 64);
    }
    if (active && eh == 0) {
        float di = dinv[d];
#pragma unroll
        for (int j = 0; j < 4; ++j)
            atomicMax(&smax[fl * 4 + j], enc_f32(di * a[j]));
    }
    __syncthreads();
    if (tid < 64) pmax[(size_t)blockIdx.x * 64 + tid] = smax[tid];
}

// ----------------------------------------------- reduce pmax -> gmax (enc)
__global__ __launch_bounds__(256) void k_maxred(const unsigned* __restrict__ pmax,
                                                unsigned* __restrict__ gmax,
                                                int rows, int rpb) {
    __shared__ unsigned smax[64];
    const int tid = threadIdx.x;
    const int c = tid & 63;
    const int w = tid >> 6;
    if (tid < 64) smax[tid] = ENC_NEG_INF;
    __syncthreads();
    unsigned m = ENC_NEG_INF;
    const int r0 = blockIdx.x * rpb;
    const int r1 = min(rows, r0 + rpb);
    for (int r = r0 + w; r < r1; r += 4)
        m = max(m, pmax[(size_t)r * 64 + c]);
    atomicMax(&smax[c], m);
    __syncthreads();
    if (tid < 64) atomicMax(&gmax[tid], smax[tid]);
}

__global__ void k_decode(const unsigned* __restrict__ g,
                         const float* __restrict__ bc,
                         float* __restrict__ out) {
    out[threadIdx.x] = dec_f32(g[threadIdx.x]) + bc[threadIdx.x];
}

// ---------------------------------------------------------------------------
extern "C" void kernel_launch(void* const* d_in, const int* in_sizes, int n_in,
                              void* d_out, int out_size, void* d_ws, size_t ws_size,
                              hipStream_t stream) {
    const float* x    = (const float*)d_in[0];
    const int*   ei   = (const int*)d_in[1];  // [2,E]: row0=src, row1=dst
    const float* W0   = (const float*)d_in[3];
    const float* b0   = (const float*)d_in[4];
    const float* W1   = (const float*)d_in[5];
    const float* b1   = (const float*)d_in[6];
    const float* W2   = (const float*)d_in[7];
    const float* b2   = (const float*)d_in[8];
    const float* Wlin = (const float*)d_in[9];
    const float* blin = (const float*)d_in[10];
    float* out = (float*)d_out;

    const int N = in_sizes[2];
    const int E = in_sizes[1] / 2;
    const int* src = ei;
    const int* dst = ei + E;

    size_t off = 0;
    auto carve = [&](size_t bytes) {
        void* p = (char*)d_ws + off;
        off += (bytes + 255) & ~(size_t)255;
        return p;
    };
    const int NB    = (N + 127) / 128;
    const int L     = NB * 256;
    const int chunk = (E + 255) / 256;
    const int nbA64 = (N + 3) / 4;        // agg64 blocks (4 dst/block)

    float*          dinv = (float*)carve((size_t)N * 4);
    int*            rofs = (int*)carve((size_t)(N + 1) * 4);
    int*            T    = (int*)carve((size_t)L * 4);
    int*            T2   = (int*)carve((size_t)L * 4);
    int*            bsums = (int*)carve(1024 * 4);
    int*            bofs  = (int*)carve(1024 * 4);
    unsigned*       eb   = (unsigned*)carve((size_t)E * 4);
    unsigned short* csr  = (unsigned short*)carve((size_t)E * 2);
    _Float16*       tmpA = (_Float16*)carve((size_t)N * 128 * 2);
    _Float16*       tmpB = (_Float16*)carve((size_t)N * 128 * 2);
    _Float16*       tmp64 = (_Float16*)carve((size_t)N * 64 * 2);
    unsigned*       pmax = (unsigned*)carve((size_t)nbA64 * 64 * 4);
    unsigned*       gmax = (unsigned*)carve(64 * 4);
    float*          bc   = (float*)carve(64 * 4);
    _Float16*       w0p  = (_Float16*)carve(256 * 128 * 2);
    _Float16*       w1p  = (_Float16*)carve(128 * 128 * 2);
    _Float16*       w2p  = (_Float16*)carve(128 * 128 * 2);
    _Float16*       wcp  = (_Float16*)carve(128 * 64 * 2);
    (void)ws_size; (void)n_in; (void)out_size;

    const int nbG  = (N + 95) / 96;
    const int nbAg = (N + 3) / 4;
    const int nbS  = (L + 1023) / 1024;
    const int RED  = 125;                 // maxred blocks
    const int rpb  = (nbA64 + RED - 1) / RED;

    k_pack_all<<<129, 64, 0, stream>>>(W0, W1, W2, w0p, w1p, w2p, gmax);
    k_wc<<<17, 64, 0, stream>>>(W2, Wlin, b2, blin, wcp, bc);

    // graph build: hist -> scan(T) -> partition -> per-bucket counting sort
    k_hist<<<256, 256, 0, stream>>>(dst, T, E, NB, chunk);
    k_scan1<<<nbS, 1024, 0, stream>>>(T, T2, bsums, L);
    k_scan2<<<1, 1024, 0, stream>>>(bsums, bofs, nbS);
    k_scan3<<<(L + 255) / 256, 256, 0, stream>>>(T2, bofs, L);
    k_part<<<256, 256, 0, stream>>>(src, dst, T2, eb, E, NB, chunk);
    k_build<<<NB, 256, 0, stream>>>(eb, T2, csr, rofs, dinv, N, E, NB);

    // layer 1 (A = fp32 x)
    k_gemm<256, 128, 0><<<nbG, 256, 0, stream>>>(x, w0p, dinv, tmpA, N);
    k_agg<<<nbAg, 256, 0, stream>>>(tmpA, dinv, rofs, csr, b0, tmpB, N);
    // layer 2
    k_gemm<128, 128, 1><<<nbG, 256, 0, stream>>>(tmpB, w1p, dinv, tmpA, N);
    k_agg<<<nbAg, 256, 0, stream>>>(tmpA, dinv, rofs, csr, b1, tmpB, N);
    // layer 3 (fused tail): tmp64 = dinv * (h2 @ Wc); agg64 + max pool
    k_gemm<128, 64, 1><<<nbG, 256, 0, stream>>>(tmpB, wcp, dinv, tmp64, N);
    k_agg64max<<<nbA64, 256, 0, stream>>>(tmp64, dinv, rofs, csr, pmax, N);
    k_maxred<<<RED, 256, 0, stream>>>(pmax, gmax, nbA64, rpb);
    k_decode<<<1, 64, 0, stream>>>(gmax, bc, out);
}